// Round 12
// baseline (246.268 us; speedup 1.0000x reference)
//
#include <hip/hip_runtime.h>
#include <hip/hip_bf16.h>
#include <stdint.h>

typedef unsigned short u16;
typedef __attribute__((ext_vector_type(4))) float f32x4;
typedef __attribute__((ext_vector_type(16))) float f32x16;
typedef __attribute__((ext_vector_type(8))) __bf16 bf16x8;
typedef __attribute__((ext_vector_type(2))) unsigned int u32x2;

__device__ __forceinline__ u16 f2bf(float f) {
  union { float f; uint32_t u; } x; x.f = f;
  const uint32_t u = x.u;
  return (u16)((u + 0x7fffu + ((u >> 16) & 1u)) >> 16);
}

// Q pre-scale: 1/sqrt(64) * log2(e), so softmax runs in exp2 domain.
#define QSCALE 0.1803368801111244f

// ------------------------------------------------------- fp32 -> bf16 cast
__global__ void cvt_f32_bf16(const float* __restrict__ in, u16* __restrict__ out,
                             int n) {
  const int i = (blockIdx.x * blockDim.x + threadIdx.x) * 4;
  if (i < n) {
    const float4 v = *(const float4*)(in + i);
    ushort4 o;
    o.x = f2bf(v.x); o.y = f2bf(v.y); o.z = f2bf(v.z); o.w = f2bf(v.w);
    *(ushort4*)(out + i) = o;
  }
}

// ------------------------- transpose + cast: f32 [R][Cc] -> bf16 [Cc][R]
__global__ void transpose_cvt(const float* __restrict__ in, u16* __restrict__ out,
                              int R, int Cc) {
  __shared__ u16 tile[64][66];
  const int tx = threadIdx.x, ty = threadIdx.y;
  const int c0 = blockIdx.x * 64, r0 = blockIdx.y * 64;
#pragma unroll
  for (int i = 0; i < 4; ++i)
    tile[ty + i * 16][tx] = f2bf(in[(size_t)(r0 + ty + i * 16) * Cc + c0 + tx]);
  __syncthreads();
#pragma unroll
  for (int i = 0; i < 4; ++i)
    out[(size_t)(c0 + ty + i * 16) * R + r0 + tx] = tile[tx][ty + i * 16];
}

// ---------------- per-head V transpose: [2048][64] -> [64][2048] (bf16)
__global__ void transpose_v(const u16* __restrict__ V, u16* __restrict__ VT) {
  __shared__ u16 tile[64][66];
  const int tx = threadIdx.x, ty = threadIdx.y;
  const int r0 = blockIdx.x * 64;                 // t-tile
  const size_t ho = (size_t)blockIdx.y * 2048 * 64;
  const u16* in = V + ho;
  u16* out = VT + ho;
#pragma unroll
  for (int i = 0; i < 4; ++i)
    tile[ty + i * 16][tx] = in[(size_t)(r0 + ty + i * 16) * 64 + tx];
  __syncthreads();
#pragma unroll
  for (int i = 0; i < 4; ++i)
    out[(size_t)(ty + i * 16) * 2048 + r0 + tx] = tile[tx][ty + i * 16];
}

// ---------------------------------------------------------------- GEMM
// A [M][K] bf16 row-major, BT [N][K] bf16 (B transposed). 128x128 tile, BK=32.
// MODE 0: write out[M][N] as FP32.  MODE 1: scatter QKV (bf16) -> Q/K/V
// [B,H,T,D], with Q pre-scaled by QSCALE (attention runs exp2-domain softmax).
template <int MODE>
__global__ __launch_bounds__(256) void gemm_bt(
    const u16* __restrict__ A, const u16* __restrict__ BT,
    float* __restrict__ out, u16* __restrict__ Qo, u16* __restrict__ Ko,
    u16* __restrict__ Vo, int M, int N, int K) {
  __shared__ u16 Asm_[128 * 32];
  __shared__ u16 Bsm_[128 * 32];
  const int tid = threadIdx.x;
  const int wid = tid >> 6, lane = tid & 63;
  const int wm = wid >> 1, wn = wid & 1;
  const int l15 = lane & 15, l4 = lane >> 4;
  const int bm = blockIdx.y, bn = blockIdx.x;

  const u16* Ag = A + (size_t)bm * 128 * K;
  const u16* Bg = BT + (size_t)bn * 128 * K;

  f32x4 acc[4][4] = {};

  const int srow = lane >> 2;        // 0..15
  const int scol = (lane & 3) * 8;   // 0,8,16,24

  for (int kt = 0; kt < K; kt += 32) {
    __syncthreads();  // previous tile's LDS reads done
#pragma unroll
    for (int it = 0; it < 2; ++it) {
      const int c = it * 4 + wid;  // 0..7, wave-uniform
      const int row = c * 16 + srow;
      __builtin_amdgcn_global_load_lds(
          (const __attribute__((address_space(1))) uint32_t*)(Ag + (size_t)row * K + kt + scol),
          (__attribute__((address_space(3))) uint32_t*)(&Asm_[c * 512]), 16, 0, 0);
      __builtin_amdgcn_global_load_lds(
          (const __attribute__((address_space(1))) uint32_t*)(Bg + (size_t)row * K + kt + scol),
          (__attribute__((address_space(3))) uint32_t*)(&Bsm_[c * 512]), 16, 0, 0);
    }
    __syncthreads();  // drains vmcnt(0) -> LDS ready

    bf16x8 af[4], bfr[4];
#pragma unroll
    for (int m = 0; m < 4; ++m)
      af[m] = *(const bf16x8*)&Asm_[(wm * 64 + m * 16 + l15) * 32 + l4 * 8];
#pragma unroll
    for (int n = 0; n < 4; ++n)
      bfr[n] = *(const bf16x8*)&Bsm_[(wn * 64 + n * 16 + l15) * 32 + l4 * 8];
#pragma unroll
    for (int m = 0; m < 4; ++m)
#pragma unroll
      for (int n = 0; n < 4; ++n)
        acc[m][n] = __builtin_amdgcn_mfma_f32_16x16x32_bf16(af[m], bfr[n], acc[m][n], 0, 0, 0);
  }

  const int row0 = bm * 128 + wm * 64;
  const int col0 = bn * 128 + wn * 64;
#pragma unroll
  for (int m = 0; m < 4; ++m) {
#pragma unroll
    for (int n = 0; n < 4; ++n) {
#pragma unroll
      for (int j = 0; j < 4; ++j) {
        const int row = row0 + m * 16 + l4 * 4 + j;
        const int col = col0 + n * 16 + l15;
        if (MODE == 1) {
          const int sec = col >> 10, c = col & 1023;
          const int h = c >> 6, d = c & 63;
          const int b = row >> 11, t = row & 2047;
          float av = acc[m][n][j];
          if (sec == 0) av *= QSCALE;  // pre-scale Q for exp2-domain softmax
          u16* dst = (sec == 0) ? Qo : (sec == 1) ? Ko : Vo;
          dst[(((size_t)(b * 16 + h)) * 2048 + t) * 64 + d] = f2bf(av);
        } else {
          out[(size_t)row * N + col] = acc[m][n][j];  // fp32 output
        }
      }
    }
  }
}

// ---------------------------------------------------------------- attention
// Q,K [B,H,T,D] bf16 (Q pre-scaled by QSCALE); VT [B,H,D,T] bf16.
// Y [B*T][C] bf16 (c = h*64+d).
// grid (32, 64), block 128 (2 waves x 32 q-rows, 64-row q-tile) -> 2048
// blocks = 8 blocks/CU (4 waves/SIMD; was grid-starved at 4 blocks/CU).
// qt = blockIdx.x ^ M8[(blockIdx.y>>3)&7]: complementary-mask XOR remap keeps
// per-CU causal workload uniform under modular placement.
// Swapped-MFMA: S^T = mfma_32x32x16(K,Q) -> lane owns one q-row; per-lane
// scalar m/l; defer-max; P->B-frag via cvt_pk + permlane32_swap; O^T accum.
__global__ __launch_bounds__(128) void attn_fwd(const u16* __restrict__ Qp,
                                                const u16* __restrict__ Kp,
                                                const u16* __restrict__ VTp,
                                                u16* __restrict__ Y) {
  constexpr int DP = 72;       // padded row (16B-aligned; 4-way alias on b128)
  constexpr float THR = 11.0f; // defer-max threshold (log2-units; P <= 2^11)
  __shared__ u16 Ks[64 * DP];  // K[key][d]
  __shared__ u16 Vt[64 * DP];  // V^T[d][key]

  static const int M8c = 0;  // (placeholder to keep layout clear)
  const uint32_t masks[8] = {0u, 31u, 5u, 26u, 10u, 21u, 15u, 16u};
  const int qt = (int)blockIdx.x ^ (int)masks[(blockIdx.y >> 3) & 7];
  const int bh = blockIdx.y;
  const int b = bh >> 4, h = bh & 15;
  const int tid = threadIdx.x, wid = tid >> 6, lane = tid & 63;
  const int l31 = lane & 31, hb = lane >> 5;
  (void)M8c;

  const size_t head_off = (size_t)bh * 2048 * 64;
  const u16* Kh = Kp + head_off;     // [2048][64]
  const u16* VTh = VTp + head_off;   // [64][2048]

  const int qg = qt * 64 + wid * 32 + l31;  // my q row within head
  const u16* Qrow = Qp + head_off + (size_t)qg * 64;

  // Q fragment (B-operand): lane holds Q[q=l31][dstep*16 + hb*8 + i]
  bf16x8 qf[4];
#pragma unroll
  for (int d = 0; d < 4; ++d)
    qf[d] = *(const bf16x8*)(Qrow + d * 16 + hb * 8);

  float m_ = -1e30f, l_ = 0.f;
  f32x16 oacc[2] = {};  // O^T: col=q=l31; rows d = (r&3)+8*(r>>2)+4*hb +32*nb

  const int nt = qt + 1;
  for (int kt = 0; kt < nt; ++kt) {
    __syncthreads();  // previous tile's LDS consumers done
#pragma unroll
    for (int it = 0; it < 4; ++it) {
      const int idx = it * 128 + tid;   // 0..511
      const int r = idx >> 3;           // 0..63
      const int c = (idx & 7) * 8;      // 0..56
      *(bf16x8*)&Ks[r * DP + c] = *(const bf16x8*)(Kh + (size_t)(kt * 64 + r) * 64 + c);
      *(bf16x8*)&Vt[r * DP + c] = *(const bf16x8*)(VTh + (size_t)r * 2048 + kt * 64 + c);
    }
    __syncthreads();

    const bool diag = (kt == qt);

#pragma unroll
    for (int kb2 = 0; kb2 < 2; ++kb2) {  // 32-key subtile
      // ---- S^T = K Q^T : lane holds 16 keys for q=l31
      f32x16 s = {};
      __builtin_amdgcn_s_setprio(1);
#pragma unroll
      for (int d = 0; d < 4; ++d) {
        const bf16x8 kf = *(const bf16x8*)&Ks[(kb2 * 32 + l31) * DP + d * 16 + hb * 8];
        s = __builtin_amdgcn_mfma_f32_32x32x16_bf16(kf, qf[d], s, 0, 0, 0);
      }
      __builtin_amdgcn_s_setprio(0);

      // ---- causal mask (diag tiles only); key = kbase + (r&3)+8*(r>>2)
      if (diag) {
        const int kbase = kt * 64 + kb2 * 32 + hb * 4;
#pragma unroll
        for (int r = 0; r < 16; ++r) {
          const int koff = (r & 3) + 8 * (r >> 2);
          if (kbase + koff > qg) s[r] = -1e30f;
        }
      }

      // ---- defer-max online softmax (per-lane scalar state)
      float pmax = s[0];
#pragma unroll
      for (int r = 1; r < 16; ++r) pmax = fmaxf(pmax, s[r]);
      if (!__all(pmax - m_ <= THR)) {
        const float fm = fmaxf(pmax, __shfl_xor(pmax, 32));
        const float mnew = fmaxf(m_, fm);
        const float alpha = __builtin_exp2f(m_ - mnew);
        m_ = mnew;
        l_ *= alpha;
#pragma unroll
        for (int nb = 0; nb < 2; ++nb)
#pragma unroll
          for (int r = 0; r < 16; ++r) oacc[nb][r] *= alpha;
      }
#pragma unroll
      for (int r = 0; r < 16; ++r) {
        s[r] = __builtin_exp2f(s[r] - m_);
        l_ += s[r];
      }

      // ---- P -> PV B-fragment: cvt_pk pairs + permlane32_swap
      bf16x8 pb[2];
#pragma unroll
      for (int st = 0; st < 2; ++st) {
        uint32_t x0, x1, y0, y1;
        asm("v_cvt_pk_bf16_f32 %0, %1, %2" : "=v"(x0) : "v"(s[8 * st + 0]), "v"(s[8 * st + 1]));
        asm("v_cvt_pk_bf16_f32 %0, %1, %2" : "=v"(x1) : "v"(s[8 * st + 2]), "v"(s[8 * st + 3]));
        asm("v_cvt_pk_bf16_f32 %0, %1, %2" : "=v"(y0) : "v"(s[8 * st + 4]), "v"(s[8 * st + 5]));
        asm("v_cvt_pk_bf16_f32 %0, %1, %2" : "=v"(y1) : "v"(s[8 * st + 6]), "v"(s[8 * st + 7]));
        const u32x2 r0 = __builtin_amdgcn_permlane32_swap(x0, y0, false, false);
        const u32x2 r1 = __builtin_amdgcn_permlane32_swap(x1, y1, false, false);
        union { uint32_t w[4]; bf16x8 v; } u;
        u.w[0] = r0[0]; u.w[1] = r1[0]; u.w[2] = r0[1]; u.w[3] = r1[1];
        pb[st] = u.v;
      }

      // ---- O^T += V^T P^T : col=q=l31 (alpha/l stay per-lane scalars)
      __builtin_amdgcn_s_setprio(1);
#pragma unroll
      for (int nb = 0; nb < 2; ++nb)
#pragma unroll
        for (int st = 0; st < 2; ++st) {
          const bf16x8 vf = *(const bf16x8*)&Vt[(nb * 32 + l31) * DP + kb2 * 32 + st * 16 + hb * 8];
          oacc[nb] = __builtin_amdgcn_mfma_f32_32x32x16_bf16(vf, pb[st], oacc[nb], 0, 0, 0);
        }
      __builtin_amdgcn_s_setprio(0);
    }
  }

  // ---- epilogue: halves hold disjoint key-partials of l_; one swap-add
  const float lf = l_ + __shfl_xor(l_, 32);
  const float inv = 1.0f / lf;
  u16* Yrow = Y + ((size_t)b * 2048 + qg) * 1024 + h * 64;
#pragma unroll
  for (int nb = 0; nb < 2; ++nb) {
#pragma unroll
    for (int g = 0; g < 4; ++g) {  // d = 8g + 4hb + 32nb + (0..3)
      ushort4 o;
      o.x = f2bf(oacc[nb][4 * g + 0] * inv);
      o.y = f2bf(oacc[nb][4 * g + 1] * inv);
      o.z = f2bf(oacc[nb][4 * g + 2] * inv);
      o.w = f2bf(oacc[nb][4 * g + 3] * inv);
      *(ushort4*)(Yrow + nb * 32 + g * 8 + hb * 4) = o;
    }
  }
}

// ---------------------------------------------------------------- launch
extern "C" void kernel_launch(void* const* d_in, const int* in_sizes, int n_in,
                              void* d_out, int out_size, void* d_ws,
                              size_t ws_size, hipStream_t stream) {
  const float* x = (const float*)d_in[0];       // [4,2048,1024] fp32
  const float* w_qkv = (const float*)d_in[1];   // [1024,3072] fp32
  const float* w_proj = (const float*)d_in[2];  // [1024,1024] fp32
  float* out = (float*)d_out;                   // [4,2048,1024] fp32

  char* ws = (char*)d_ws;
  u16* xb = (u16*)ws;                          // [8192][1024]  16 MB (dead after QKV GEMM)
  u16* VTw = (u16*)ws;                         // [B,H,D,T]     16 MB (aliases xb)
  u16* wqkvT = (u16*)(ws + 16777216);          // [3072][1024]   6 MB
  u16* wprojT = (u16*)(ws + 23068672);         // [1024][1024]   2 MB
  u16* Qw = (u16*)(ws + 25165824);             // [B,H,T,D]     16 MB
  u16* Kw = (u16*)(ws + 41943040);             // 16 MB
  u16* Vw = (u16*)(ws + 58720256);             // 16 MB
  u16* Yw = (u16*)(ws + 75497472);             // [B*T][C]      16 MB
  if (ws_size < 92274688) return;  // distinguishable failure (abs=ref max)

  cvt_f32_bf16<<<dim3(8192), dim3(256), 0, stream>>>(x, xb, 8388608);

  dim3 tb(64, 16);
  transpose_cvt<<<dim3(48, 16), tb, 0, stream>>>(w_qkv, wqkvT, 1024, 3072);
  transpose_cvt<<<dim3(16, 16), tb, 0, stream>>>(w_proj, wprojT, 1024, 1024);

  gemm_bt<1><<<dim3(24, 64), dim3(256), 0, stream>>>(
      xb, wqkvT, (float*)nullptr, Qw, Kw, Vw, 8192, 3072, 1024);

  // xb is dead now; build VT in its place.
  transpose_v<<<dim3(32, 64), tb, 0, stream>>>(Vw, VTw);

  attn_fwd<<<dim3(32, 64), dim3(128), 0, stream>>>(Qw, Kw, VTw, Yw);

  gemm_bt<0><<<dim3(8, 64), dim3(256), 0, stream>>>(
      Yw, wprojT, out, (u16*)nullptr, (u16*)nullptr, (u16*)nullptr,
      8192, 1024, 1024);
}

// Round 13
// 216.505 us; speedup vs baseline: 1.1375x; 1.1375x over previous
//
#include <hip/hip_runtime.h>
#include <hip/hip_bf16.h>
#include <stdint.h>

typedef unsigned short u16;
typedef __attribute__((ext_vector_type(4))) float f32x4;
typedef __attribute__((ext_vector_type(16))) float f32x16;
typedef __attribute__((ext_vector_type(8))) __bf16 bf16x8;
typedef __attribute__((ext_vector_type(2))) unsigned int u32x2;

__device__ __forceinline__ u16 f2bf(float f) {
  union { float f; uint32_t u; } x; x.f = f;
  const uint32_t u = x.u;
  return (u16)((u + 0x7fffu + ((u >> 16) & 1u)) >> 16);
}

// Q pre-scale: 1/sqrt(64) * log2(e), so softmax runs in exp2 domain.
#define QSCALE 0.1803368801111244f

// ------------------------------------------------------- fp32 -> bf16 cast
__global__ void cvt_f32_bf16(const float* __restrict__ in, u16* __restrict__ out,
                             int n) {
  const int i = (blockIdx.x * blockDim.x + threadIdx.x) * 4;
  if (i < n) {
    const float4 v = *(const float4*)(in + i);
    ushort4 o;
    o.x = f2bf(v.x); o.y = f2bf(v.y); o.z = f2bf(v.z); o.w = f2bf(v.w);
    *(ushort4*)(out + i) = o;
  }
}

// ------------------------- transpose + cast: f32 [R][Cc] -> bf16 [Cc][R]
__global__ void transpose_cvt(const float* __restrict__ in, u16* __restrict__ out,
                              int R, int Cc) {
  __shared__ u16 tile[64][66];
  const int tx = threadIdx.x, ty = threadIdx.y;
  const int c0 = blockIdx.x * 64, r0 = blockIdx.y * 64;
#pragma unroll
  for (int i = 0; i < 4; ++i)
    tile[ty + i * 16][tx] = f2bf(in[(size_t)(r0 + ty + i * 16) * Cc + c0 + tx]);
  __syncthreads();
#pragma unroll
  for (int i = 0; i < 4; ++i)
    out[(size_t)(c0 + ty + i * 16) * R + r0 + tx] = tile[tx][ty + i * 16];
}

// ---------------------------------------------------------------- GEMM
// A [M][K] bf16 row-major, BT [N][K] bf16 (B transposed). 128x128 tile, BK=32.
// MODE 0: write out[M][N] as FP32.  MODE 1: scatter QKV (bf16): Q (pre-scaled
// by QSCALE) and K -> [B,H,T,D]; V -> TRANSPOSED [B,H,D,T] (feeds attention's
// VT operand directly; kills the separate transpose_v pass).
template <int MODE>
__global__ __launch_bounds__(256) void gemm_bt(
    const u16* __restrict__ A, const u16* __restrict__ BT,
    float* __restrict__ out, u16* __restrict__ Qo, u16* __restrict__ Ko,
    u16* __restrict__ VTo, int M, int N, int K) {
  __shared__ u16 Asm_[128 * 32];
  __shared__ u16 Bsm_[128 * 32];
  const int tid = threadIdx.x;
  const int wid = tid >> 6, lane = tid & 63;
  const int wm = wid >> 1, wn = wid & 1;
  const int l15 = lane & 15, l4 = lane >> 4;
  const int bm = blockIdx.y, bn = blockIdx.x;

  const u16* Ag = A + (size_t)bm * 128 * K;
  const u16* Bg = BT + (size_t)bn * 128 * K;

  f32x4 acc[4][4] = {};

  const int srow = lane >> 2;        // 0..15
  const int scol = (lane & 3) * 8;   // 0,8,16,24

  for (int kt = 0; kt < K; kt += 32) {
    __syncthreads();  // previous tile's LDS reads done
#pragma unroll
    for (int it = 0; it < 2; ++it) {
      const int c = it * 4 + wid;  // 0..7, wave-uniform
      const int row = c * 16 + srow;
      __builtin_amdgcn_global_load_lds(
          (const __attribute__((address_space(1))) uint32_t*)(Ag + (size_t)row * K + kt + scol),
          (__attribute__((address_space(3))) uint32_t*)(&Asm_[c * 512]), 16, 0, 0);
      __builtin_amdgcn_global_load_lds(
          (const __attribute__((address_space(1))) uint32_t*)(Bg + (size_t)row * K + kt + scol),
          (__attribute__((address_space(3))) uint32_t*)(&Bsm_[c * 512]), 16, 0, 0);
    }
    __syncthreads();  // drains vmcnt(0) -> LDS ready

    bf16x8 af[4], bfr[4];
#pragma unroll
    for (int m = 0; m < 4; ++m)
      af[m] = *(const bf16x8*)&Asm_[(wm * 64 + m * 16 + l15) * 32 + l4 * 8];
#pragma unroll
    for (int n = 0; n < 4; ++n)
      bfr[n] = *(const bf16x8*)&Bsm_[(wn * 64 + n * 16 + l15) * 32 + l4 * 8];
#pragma unroll
    for (int m = 0; m < 4; ++m)
#pragma unroll
      for (int n = 0; n < 4; ++n)
        acc[m][n] = __builtin_amdgcn_mfma_f32_16x16x32_bf16(af[m], bfr[n], acc[m][n], 0, 0, 0);
  }

  const int row0 = bm * 128 + wm * 64;
  const int col0 = bn * 128 + wn * 64;
#pragma unroll
  for (int m = 0; m < 4; ++m) {
#pragma unroll
    for (int n = 0; n < 4; ++n) {
#pragma unroll
      for (int j = 0; j < 4; ++j) {
        const int row = row0 + m * 16 + l4 * 4 + j;
        const int col = col0 + n * 16 + l15;
        if (MODE == 1) {
          const int sec = col >> 10, c = col & 1023;
          const int h = c >> 6, d = c & 63;
          const int b = row >> 11, t = row & 2047;
          const size_t head = (size_t)(b * 16 + h);
          float av = acc[m][n][j];
          if (sec == 0) {
            av *= QSCALE;  // pre-scale Q for exp2-domain softmax
            Qo[(head * 2048 + t) * 64 + d] = f2bf(av);
          } else if (sec == 1) {
            Ko[(head * 2048 + t) * 64 + d] = f2bf(av);
          } else {
            // V transposed: [B,H,D,T]; j varies t -> 4 consecutive u16
            VTo[(head * 64 + d) * 2048 + t] = f2bf(av);
          }
        } else {
          out[(size_t)row * N + col] = acc[m][n][j];  // fp32 output
        }
      }
    }
  }
}

// ---------------------------------------------------------------- attention
// Q,K [B,H,T,D] bf16 (Q pre-scaled by QSCALE); VT [B,H,D,T] bf16.
// Y [B*T][C] bf16 (c = h*64+d).
// grid (16, 64), block 256 (4 waves x 32 q-rows). Swapped-MFMA structure:
//   S^T = mfma_32x32x16(K_frag, Q_frag): col = lane&31 = q -> each lane owns
//   ONE q-row; m/l are per-lane scalars; in-lane row reduce (+1 shfl_xor(32)
//   rare-path only, defer-max THR).
//   P -> PV B-fragment via v_cvt_pk_bf16_f32 + permlane32_swap.
//   PV = mfma(VT_frag, P_frag): O^T with col = q = l31 -> alpha rescale is a
//   per-lane scalar over 32 regs. No P LDS staging, no fences.
// qt XOR remap {0,15,5,10}: balances per-CU causal workload under modular
// round-robin placement (each CU's 4 co-resident qts sum to 30).
__global__ __launch_bounds__(256, 4) void attn_fwd(const u16* __restrict__ Qp,
                                                   const u16* __restrict__ Kp,
                                                   const u16* __restrict__ VTp,
                                                   u16* __restrict__ Y) {
  constexpr int DP = 72;       // padded row (16B-aligned; 4-way alias on b128)
  constexpr float THR = 11.0f; // defer-max threshold (log2-units; P <= 2^11)
  __shared__ u16 Ks[64 * DP];  // K[key][d]
  __shared__ u16 Vt[64 * DP];  // V^T[d][key]

  const int xorm = (int)((0x0A050F00u >> ((blockIdx.y >> 4) * 8)) & 15u);  // {0,15,5,10}
  const int qt = (int)blockIdx.x ^ xorm;  // 128-row q-tile (bijective remap)
  const int bh = blockIdx.y;
  const int b = bh >> 4, h = bh & 15;
  const int tid = threadIdx.x, wid = tid >> 6, lane = tid & 63;
  const int l31 = lane & 31, hb = lane >> 5;

  const size_t head_off = (size_t)bh * 2048 * 64;
  const u16* Kh = Kp + head_off;     // [2048][64]
  const u16* VTh = VTp + head_off;   // [64][2048]

  const int qg = qt * 128 + wid * 32 + l31;  // my q row within head
  const u16* Qrow = Qp + head_off + (size_t)qg * 64;

  // Q fragment (B-operand): lane holds Q[q=l31][dstep*16 + hb*8 + i]
  bf16x8 qf[4];
#pragma unroll
  for (int d = 0; d < 4; ++d)
    qf[d] = *(const bf16x8*)(Qrow + d * 16 + hb * 8);

  float m_ = -1e30f, l_ = 0.f;
  f32x16 oacc[2] = {};  // O^T: col=q=l31; rows d = (r&3)+8*(r>>2)+4*hb +32*nb

  const int nt = 2 * qt + 2;
  for (int kt = 0; kt < nt; ++kt) {
    __syncthreads();  // previous tile's LDS consumers done
#pragma unroll
    for (int it = 0; it < 2; ++it) {
      const int idx = it * 256 + tid;   // 0..511
      const int r = idx >> 3;           // 0..63
      const int c = (idx & 7) * 8;      // 0..56
      *(bf16x8*)&Ks[r * DP + c] = *(const bf16x8*)(Kh + (size_t)(kt * 64 + r) * 64 + c);
      *(bf16x8*)&Vt[r * DP + c] = *(const bf16x8*)(VTh + (size_t)r * 2048 + kt * 64 + c);
    }
    __syncthreads();

    const bool diag = (kt >= 2 * qt);

#pragma unroll
    for (int kb2 = 0; kb2 < 2; ++kb2) {  // 32-key subtile
      // ---- S^T = K Q^T : lane holds 16 keys for q=l31
      f32x16 s = {};
      __builtin_amdgcn_s_setprio(1);
#pragma unroll
      for (int d = 0; d < 4; ++d) {
        const bf16x8 kf = *(const bf16x8*)&Ks[(kb2 * 32 + l31) * DP + d * 16 + hb * 8];
        s = __builtin_amdgcn_mfma_f32_32x32x16_bf16(kf, qf[d], s, 0, 0, 0);
      }
      __builtin_amdgcn_s_setprio(0);

      // ---- causal mask (diag tiles only); key = kbase + (r&3)+8*(r>>2)
      if (diag) {
        const int kbase = kt * 64 + kb2 * 32 + hb * 4;
#pragma unroll
        for (int r = 0; r < 16; ++r) {
          const int koff = (r & 3) + 8 * (r >> 2);
          if (kbase + koff > qg) s[r] = -1e30f;
        }
      }

      // ---- defer-max online softmax (per-lane scalar state)
      float pmax = s[0];
#pragma unroll
      for (int r = 1; r < 16; ++r) pmax = fmaxf(pmax, s[r]);
      if (!__all(pmax - m_ <= THR)) {
        const float fm = fmaxf(pmax, __shfl_xor(pmax, 32));
        const float mnew = fmaxf(m_, fm);
        const float alpha = __builtin_exp2f(m_ - mnew);
        m_ = mnew;
        l_ *= alpha;
#pragma unroll
        for (int nb = 0; nb < 2; ++nb)
#pragma unroll
          for (int r = 0; r < 16; ++r) oacc[nb][r] *= alpha;
      }
#pragma unroll
      for (int r = 0; r < 16; ++r) {
        s[r] = __builtin_exp2f(s[r] - m_);
        l_ += s[r];
      }

      // ---- P -> PV B-fragment: cvt_pk pairs + permlane32_swap
      bf16x8 pb[2];
#pragma unroll
      for (int st = 0; st < 2; ++st) {
        uint32_t x0, x1, y0, y1;
        asm("v_cvt_pk_bf16_f32 %0, %1, %2" : "=v"(x0) : "v"(s[8 * st + 0]), "v"(s[8 * st + 1]));
        asm("v_cvt_pk_bf16_f32 %0, %1, %2" : "=v"(x1) : "v"(s[8 * st + 2]), "v"(s[8 * st + 3]));
        asm("v_cvt_pk_bf16_f32 %0, %1, %2" : "=v"(y0) : "v"(s[8 * st + 4]), "v"(s[8 * st + 5]));
        asm("v_cvt_pk_bf16_f32 %0, %1, %2" : "=v"(y1) : "v"(s[8 * st + 6]), "v"(s[8 * st + 7]));
        const u32x2 r0 = __builtin_amdgcn_permlane32_swap(x0, y0, false, false);
        const u32x2 r1 = __builtin_amdgcn_permlane32_swap(x1, y1, false, false);
        union { uint32_t w[4]; bf16x8 v; } u;
        u.w[0] = r0[0]; u.w[1] = r1[0]; u.w[2] = r0[1]; u.w[3] = r1[1];
        pb[st] = u.v;
      }

      // ---- O^T += V^T P^T : col=q=l31 (alpha/l stay per-lane scalars)
      __builtin_amdgcn_s_setprio(1);
#pragma unroll
      for (int nb = 0; nb < 2; ++nb)
#pragma unroll
        for (int st = 0; st < 2; ++st) {
          const bf16x8 vf = *(const bf16x8*)&Vt[(nb * 32 + l31) * DP + kb2 * 32 + st * 16 + hb * 8];
          oacc[nb] = __builtin_amdgcn_mfma_f32_32x32x16_bf16(vf, pb[st], oacc[nb], 0, 0, 0);
        }
      __builtin_amdgcn_s_setprio(0);
    }
  }

  // ---- epilogue: halves hold disjoint key-partials of l_; one swap-add
  const float lf = l_ + __shfl_xor(l_, 32);
  const float inv = 1.0f / lf;
  u16* Yrow = Y + ((size_t)b * 2048 + qg) * 1024 + h * 64;
#pragma unroll
  for (int nb = 0; nb < 2; ++nb) {
#pragma unroll
    for (int g = 0; g < 4; ++g) {  // d = 8g + 4hb + 32nb + (0..3)
      ushort4 o;
      o.x = f2bf(oacc[nb][4 * g + 0] * inv);
      o.y = f2bf(oacc[nb][4 * g + 1] * inv);
      o.z = f2bf(oacc[nb][4 * g + 2] * inv);
      o.w = f2bf(oacc[nb][4 * g + 3] * inv);
      *(ushort4*)(Yrow + nb * 32 + g * 8 + hb * 4) = o;
    }
  }
}

// ---------------------------------------------------------------- launch
extern "C" void kernel_launch(void* const* d_in, const int* in_sizes, int n_in,
                              void* d_out, int out_size, void* d_ws,
                              size_t ws_size, hipStream_t stream) {
  const float* x = (const float*)d_in[0];       // [4,2048,1024] fp32
  const float* w_qkv = (const float*)d_in[1];   // [1024,3072] fp32
  const float* w_proj = (const float*)d_in[2];  // [1024,1024] fp32
  float* out = (float*)d_out;                   // [4,2048,1024] fp32

  char* ws = (char*)d_ws;
  u16* xb = (u16*)ws;                          // [8192][1024]  16 MB
  u16* wqkvT = (u16*)(ws + 16777216);          // [3072][1024]   6 MB
  u16* wprojT = (u16*)(ws + 23068672);         // [1024][1024]   2 MB
  u16* Qw = (u16*)(ws + 25165824);             // [B,H,T,D]     16 MB
  u16* Kw = (u16*)(ws + 41943040);             // 16 MB
  u16* VTw = (u16*)(ws + 58720256);            // [B,H,D,T]     16 MB (written by GEMM)
  u16* Yw = (u16*)(ws + 75497472);             // [B*T][C]      16 MB
  if (ws_size < 92274688) return;  // distinguishable failure (abs=ref max)

  cvt_f32_bf16<<<dim3(8192), dim3(256), 0, stream>>>(x, xb, 8388608);

  dim3 tb(64, 16);
  transpose_cvt<<<dim3(48, 16), tb, 0, stream>>>(w_qkv, wqkvT, 1024, 3072);
  transpose_cvt<<<dim3(16, 16), tb, 0, stream>>>(w_proj, wprojT, 1024, 1024);

  gemm_bt<1><<<dim3(24, 64), dim3(256), 0, stream>>>(
      xb, wqkvT, (float*)nullptr, Qw, Kw, VTw, 8192, 3072, 1024);

  attn_fwd<<<dim3(16, 64), dim3(256), 0, stream>>>(Qw, Kw, VTw, Yw);

  gemm_bt<0><<<dim3(8, 64), dim3(256), 0, stream>>>(
      Yw, wprojT, out, (u16*)nullptr, (u16*)nullptr, (u16*)nullptr,
      8192, 1024, 1024);
}

// Round 14
// 203.185 us; speedup vs baseline: 1.2120x; 1.0656x over previous
//
#include <hip/hip_runtime.h>
#include <hip/hip_bf16.h>
#include <stdint.h>

typedef unsigned short u16;
typedef __attribute__((ext_vector_type(4))) float f32x4;
typedef __attribute__((ext_vector_type(16))) float f32x16;
typedef __attribute__((ext_vector_type(8))) __bf16 bf16x8;
typedef __attribute__((ext_vector_type(2))) unsigned int u32x2;

__device__ __forceinline__ u16 f2bf(float f) {
  union { float f; uint32_t u; } x; x.f = f;
  const uint32_t u = x.u;
  return (u16)((u + 0x7fffu + ((u >> 16) & 1u)) >> 16);
}

// Q pre-scale: 1/sqrt(64) * log2(e), so softmax runs in exp2 domain.
#define QSCALE 0.1803368801111244f

// ------------------------------------------------------- fp32 -> bf16 cast
__global__ void cvt_f32_bf16(const float* __restrict__ in, u16* __restrict__ out,
                             int n) {
  const int i = (blockIdx.x * blockDim.x + threadIdx.x) * 4;
  if (i < n) {
    const float4 v = *(const float4*)(in + i);
    ushort4 o;
    o.x = f2bf(v.x); o.y = f2bf(v.y); o.z = f2bf(v.z); o.w = f2bf(v.w);
    *(ushort4*)(out + i) = o;
  }
}

// ------------------------- transpose + cast: f32 [R][Cc] -> bf16 [Cc][R]
__global__ void transpose_cvt(const float* __restrict__ in, u16* __restrict__ out,
                              int R, int Cc) {
  __shared__ u16 tile[64][66];
  const int tx = threadIdx.x, ty = threadIdx.y;
  const int c0 = blockIdx.x * 64, r0 = blockIdx.y * 64;
#pragma unroll
  for (int i = 0; i < 4; ++i)
    tile[ty + i * 16][tx] = f2bf(in[(size_t)(r0 + ty + i * 16) * Cc + c0 + tx]);
  __syncthreads();
#pragma unroll
  for (int i = 0; i < 4; ++i)
    out[(size_t)(c0 + ty + i * 16) * R + r0 + tx] = tile[tx][ty + i * 16];
}

// ---------------- per-head V transpose: [2048][64] -> [64][2048] (bf16)
// LDS-tiled, coalesced on both sides. Cheaper than fusing a scattered
// write into the GEMM epilogue (R13: fusion cost +51us on the GEMM).
__global__ void transpose_v(const u16* __restrict__ V, u16* __restrict__ VT) {
  __shared__ u16 tile[64][66];
  const int tx = threadIdx.x, ty = threadIdx.y;
  const int r0 = blockIdx.x * 64;                 // t-tile
  const size_t ho = (size_t)blockIdx.y * 2048 * 64;
  const u16* in = V + ho;
  u16* out = VT + ho;
#pragma unroll
  for (int i = 0; i < 4; ++i)
    tile[ty + i * 16][tx] = in[(size_t)(r0 + ty + i * 16) * 64 + tx];
  __syncthreads();
#pragma unroll
  for (int i = 0; i < 4; ++i)
    out[(size_t)(ty + i * 16) * 2048 + r0 + tx] = tile[tx][ty + i * 16];
}

// ---------------------------------------------------------------- GEMM
// A [M][K] bf16 row-major, BT [N][K] bf16 (B transposed). 128x128 tile, BK=32.
// MODE 0: write out[M][N] as FP32.  MODE 1: scatter QKV (bf16) -> Q/K/V
// [B,H,T,D], with Q pre-scaled by QSCALE (attention runs exp2-domain softmax).
template <int MODE>
__global__ __launch_bounds__(256) void gemm_bt(
    const u16* __restrict__ A, const u16* __restrict__ BT,
    float* __restrict__ out, u16* __restrict__ Qo, u16* __restrict__ Ko,
    u16* __restrict__ Vo, int M, int N, int K) {
  __shared__ u16 Asm_[128 * 32];
  __shared__ u16 Bsm_[128 * 32];
  const int tid = threadIdx.x;
  const int wid = tid >> 6, lane = tid & 63;
  const int wm = wid >> 1, wn = wid & 1;
  const int l15 = lane & 15, l4 = lane >> 4;
  const int bm = blockIdx.y, bn = blockIdx.x;

  const u16* Ag = A + (size_t)bm * 128 * K;
  const u16* Bg = BT + (size_t)bn * 128 * K;

  f32x4 acc[4][4] = {};

  const int srow = lane >> 2;        // 0..15
  const int scol = (lane & 3) * 8;   // 0,8,16,24

  for (int kt = 0; kt < K; kt += 32) {
    __syncthreads();  // previous tile's LDS reads done
#pragma unroll
    for (int it = 0; it < 2; ++it) {
      const int c = it * 4 + wid;  // 0..7, wave-uniform
      const int row = c * 16 + srow;
      __builtin_amdgcn_global_load_lds(
          (const __attribute__((address_space(1))) uint32_t*)(Ag + (size_t)row * K + kt + scol),
          (__attribute__((address_space(3))) uint32_t*)(&Asm_[c * 512]), 16, 0, 0);
      __builtin_amdgcn_global_load_lds(
          (const __attribute__((address_space(1))) uint32_t*)(Bg + (size_t)row * K + kt + scol),
          (__attribute__((address_space(3))) uint32_t*)(&Bsm_[c * 512]), 16, 0, 0);
    }
    __syncthreads();  // drains vmcnt(0) -> LDS ready

    bf16x8 af[4], bfr[4];
#pragma unroll
    for (int m = 0; m < 4; ++m)
      af[m] = *(const bf16x8*)&Asm_[(wm * 64 + m * 16 + l15) * 32 + l4 * 8];
#pragma unroll
    for (int n = 0; n < 4; ++n)
      bfr[n] = *(const bf16x8*)&Bsm_[(wn * 64 + n * 16 + l15) * 32 + l4 * 8];
#pragma unroll
    for (int m = 0; m < 4; ++m)
#pragma unroll
      for (int n = 0; n < 4; ++n)
        acc[m][n] = __builtin_amdgcn_mfma_f32_16x16x32_bf16(af[m], bfr[n], acc[m][n], 0, 0, 0);
  }

  const int row0 = bm * 128 + wm * 64;
  const int col0 = bn * 128 + wn * 64;
#pragma unroll
  for (int m = 0; m < 4; ++m) {
#pragma unroll
    for (int n = 0; n < 4; ++n) {
#pragma unroll
      for (int j = 0; j < 4; ++j) {
        const int row = row0 + m * 16 + l4 * 4 + j;
        const int col = col0 + n * 16 + l15;
        if (MODE == 1) {
          const int sec = col >> 10, c = col & 1023;
          const int h = c >> 6, d = c & 63;
          const int b = row >> 11, t = row & 2047;
          float av = acc[m][n][j];
          if (sec == 0) av *= QSCALE;  // pre-scale Q for exp2-domain softmax
          u16* dst = (sec == 0) ? Qo : (sec == 1) ? Ko : Vo;
          dst[(((size_t)(b * 16 + h)) * 2048 + t) * 64 + d] = f2bf(av);
        } else {
          out[(size_t)row * N + col] = acc[m][n][j];  // fp32 output
        }
      }
    }
  }
}

// ---------------------------------------------------------------- attention
// Q,K [B,H,T,D] bf16 (Q pre-scaled by QSCALE); VT [B,H,D,T] bf16.
// Y [B*T][C] bf16 (c = h*64+d).
// grid (16, 64), block 256 (4 waves x 32 q-rows). Swapped-MFMA structure
// (R11) + double-buffered LDS with register prefetch: ONE barrier per tile,
// next tile's K/V global loads issue before compute and land after it.
// qt XOR remap {0,15,5,10} balances per-CU causal workload.
__global__ __launch_bounds__(256, 4) void attn_fwd(const u16* __restrict__ Qp,
                                                   const u16* __restrict__ Kp,
                                                   const u16* __restrict__ VTp,
                                                   u16* __restrict__ Y) {
  constexpr int DP = 72;       // padded row (16B-aligned)
  constexpr float THR = 11.0f; // defer-max threshold (log2-units; P <= 2^11)
  __shared__ u16 Ks[2][64 * DP];  // K[key][d], double-buffered
  __shared__ u16 Vt[2][64 * DP];  // V^T[d][key], double-buffered

  const int xorm = (int)((0x0A050F00u >> ((blockIdx.y >> 4) * 8)) & 15u);  // {0,15,5,10}
  const int qt = (int)blockIdx.x ^ xorm;  // 128-row q-tile (bijective remap)
  const int bh = blockIdx.y;
  const int b = bh >> 4, h = bh & 15;
  const int tid = threadIdx.x, lane = tid & 63;
  const int wid = tid >> 6;
  const int l31 = lane & 31, hb = lane >> 5;

  const size_t head_off = (size_t)bh * 2048 * 64;
  const u16* Kh = Kp + head_off;     // [2048][64]
  const u16* VTh = VTp + head_off;   // [64][2048]

  const int qg = qt * 128 + wid * 32 + l31;  // my q row within head
  const u16* Qrow = Qp + head_off + (size_t)qg * 64;

  // Q fragment (B-operand): lane holds Q[q=l31][dstep*16 + hb*8 + i]
  bf16x8 qf[4];
#pragma unroll
  for (int d = 0; d < 4; ++d)
    qf[d] = *(const bf16x8*)(Qrow + d * 16 + hb * 8);

  float m_ = -1e30f, l_ = 0.f;
  f32x16 oacc[2] = {};  // O^T: col=q=l31; rows d = (r&3)+8*(r>>2)+4*hb +32*nb

  // staging coords: idx = it*256+tid -> r = idx>>3 (0..63), c = (idx&7)*8
  const int sr = tid >> 3;          // rows for it=0: 0..31; it=1: +32
  const int sc = (tid & 7) * 8;

  bf16x8 kreg[2], vreg[2];
  auto kvload = [&](int kt) {
#pragma unroll
    for (int it = 0; it < 2; ++it) {
      const int r = sr + it * 32;
      kreg[it] = *(const bf16x8*)(Kh + (size_t)(kt * 64 + r) * 64 + sc);
      vreg[it] = *(const bf16x8*)(VTh + (size_t)r * 2048 + kt * 64 + sc);
    }
  };
  auto kvwrite = [&](int buf) {
#pragma unroll
    for (int it = 0; it < 2; ++it) {
      const int r = sr + it * 32;
      *(bf16x8*)&Ks[buf][r * DP + sc] = kreg[it];
      *(bf16x8*)&Vt[buf][r * DP + sc] = vreg[it];
    }
  };

  // prologue: stage tile 0 into buffer 0
  kvload(0);
  kvwrite(0);
  __syncthreads();

  const int nt = 2 * qt + 2;
  for (int kt = 0; kt < nt; ++kt) {
    const int cur = kt & 1;
    const bool havenext = (kt + 1 < nt);
    if (havenext) kvload(kt + 1);  // issue early; lands after compute

    const bool diag = (kt >= 2 * qt);

#pragma unroll
    for (int kb2 = 0; kb2 < 2; ++kb2) {  // 32-key subtile
      // ---- S^T = K Q^T : lane holds 16 keys for q=l31
      f32x16 s = {};
      __builtin_amdgcn_s_setprio(1);
#pragma unroll
      for (int d = 0; d < 4; ++d) {
        const bf16x8 kf = *(const bf16x8*)&Ks[cur][(kb2 * 32 + l31) * DP + d * 16 + hb * 8];
        s = __builtin_amdgcn_mfma_f32_32x32x16_bf16(kf, qf[d], s, 0, 0, 0);
      }
      __builtin_amdgcn_s_setprio(0);

      // ---- causal mask (diag tiles only); key = kbase + (r&3)+8*(r>>2)
      if (diag) {
        const int kbase = kt * 64 + kb2 * 32 + hb * 4;
#pragma unroll
        for (int r = 0; r < 16; ++r) {
          const int koff = (r & 3) + 8 * (r >> 2);
          if (kbase + koff > qg) s[r] = -1e30f;
        }
      }

      // ---- defer-max online softmax (per-lane scalar state)
      float pmax = s[0];
#pragma unroll
      for (int r = 1; r < 16; ++r) pmax = fmaxf(pmax, s[r]);
      if (!__all(pmax - m_ <= THR)) {
        const float fm = fmaxf(pmax, __shfl_xor(pmax, 32));
        const float mnew = fmaxf(m_, fm);
        const float alpha = __builtin_exp2f(m_ - mnew);
        m_ = mnew;
        l_ *= alpha;
#pragma unroll
        for (int nb = 0; nb < 2; ++nb)
#pragma unroll
          for (int r = 0; r < 16; ++r) oacc[nb][r] *= alpha;
      }
#pragma unroll
      for (int r = 0; r < 16; ++r) {
        s[r] = __builtin_exp2f(s[r] - m_);
        l_ += s[r];
      }

      // ---- P -> PV B-fragment: cvt_pk pairs + permlane32_swap
      bf16x8 pb[2];
#pragma unroll
      for (int st = 0; st < 2; ++st) {
        uint32_t x0, x1, y0, y1;
        asm("v_cvt_pk_bf16_f32 %0, %1, %2" : "=v"(x0) : "v"(s[8 * st + 0]), "v"(s[8 * st + 1]));
        asm("v_cvt_pk_bf16_f32 %0, %1, %2" : "=v"(x1) : "v"(s[8 * st + 2]), "v"(s[8 * st + 3]));
        asm("v_cvt_pk_bf16_f32 %0, %1, %2" : "=v"(y0) : "v"(s[8 * st + 4]), "v"(s[8 * st + 5]));
        asm("v_cvt_pk_bf16_f32 %0, %1, %2" : "=v"(y1) : "v"(s[8 * st + 6]), "v"(s[8 * st + 7]));
        const u32x2 r0 = __builtin_amdgcn_permlane32_swap(x0, y0, false, false);
        const u32x2 r1 = __builtin_amdgcn_permlane32_swap(x1, y1, false, false);
        union { uint32_t w[4]; bf16x8 v; } u;
        u.w[0] = r0[0]; u.w[1] = r1[0]; u.w[2] = r0[1]; u.w[3] = r1[1];
        pb[st] = u.v;
      }

      // ---- O^T += V^T P^T : col=q=l31 (alpha/l stay per-lane scalars)
      __builtin_amdgcn_s_setprio(1);
#pragma unroll
      for (int nb = 0; nb < 2; ++nb)
#pragma unroll
        for (int st = 0; st < 2; ++st) {
          const bf16x8 vf = *(const bf16x8*)&Vt[cur][(nb * 32 + l31) * DP + kb2 * 32 + st * 16 + hb * 8];
          oacc[nb] = __builtin_amdgcn_mfma_f32_32x32x16_bf16(vf, pb[st], oacc[nb], 0, 0, 0);
        }
      __builtin_amdgcn_s_setprio(0);
    }

    // write next tile into the other buffer; all waves finished reading it
    // (for tile kt-1) before the barrier that started this iteration.
    if (havenext) kvwrite(cur ^ 1);
    __syncthreads();
  }

  // ---- epilogue: halves hold disjoint key-partials of l_; one swap-add
  const float lf = l_ + __shfl_xor(l_, 32);
  const float inv = 1.0f / lf;
  u16* Yrow = Y + ((size_t)b * 2048 + qg) * 1024 + h * 64;
#pragma unroll
  for (int nb = 0; nb < 2; ++nb) {
#pragma unroll
    for (int g = 0; g < 4; ++g) {  // d = 8g + 4hb + 32nb + (0..3)
      ushort4 o;
      o.x = f2bf(oacc[nb][4 * g + 0] * inv);
      o.y = f2bf(oacc[nb][4 * g + 1] * inv);
      o.z = f2bf(oacc[nb][4 * g + 2] * inv);
      o.w = f2bf(oacc[nb][4 * g + 3] * inv);
      *(ushort4*)(Yrow + nb * 32 + g * 8 + hb * 4) = o;
    }
  }
}

// ---------------------------------------------------------------- launch
extern "C" void kernel_launch(void* const* d_in, const int* in_sizes, int n_in,
                              void* d_out, int out_size, void* d_ws,
                              size_t ws_size, hipStream_t stream) {
  const float* x = (const float*)d_in[0];       // [4,2048,1024] fp32
  const float* w_qkv = (const float*)d_in[1];   // [1024,3072] fp32
  const float* w_proj = (const float*)d_in[2];  // [1024,1024] fp32
  float* out = (float*)d_out;                   // [4,2048,1024] fp32

  char* ws = (char*)d_ws;
  u16* xb = (u16*)ws;                          // [8192][1024]  16 MB (dead after QKV GEMM)
  u16* VTw = (u16*)ws;                         // [B,H,D,T]     16 MB (aliases xb)
  u16* wqkvT = (u16*)(ws + 16777216);          // [3072][1024]   6 MB
  u16* wprojT = (u16*)(ws + 23068672);         // [1024][1024]   2 MB
  u16* Qw = (u16*)(ws + 25165824);             // [B,H,T,D]     16 MB
  u16* Kw = (u16*)(ws + 41943040);             // 16 MB
  u16* Vw = (u16*)(ws + 58720256);             // 16 MB
  u16* Yw = (u16*)(ws + 75497472);             // [B*T][C]      16 MB
  if (ws_size < 92274688) return;  // distinguishable failure (abs=ref max)

  cvt_f32_bf16<<<dim3(8192), dim3(256), 0, stream>>>(x, xb, 8388608);

  dim3 tb(64, 16);
  transpose_cvt<<<dim3(48, 16), tb, 0, stream>>>(w_qkv, wqkvT, 1024, 3072);
  transpose_cvt<<<dim3(16, 16), tb, 0, stream>>>(w_proj, wprojT, 1024, 1024);

  gemm_bt<1><<<dim3(24, 64), dim3(256), 0, stream>>>(
      xb, wqkvT, (float*)nullptr, Qw, Kw, Vw, 8192, 3072, 1024);

  // xb is dead now; build VT in its place.
  transpose_v<<<dim3(32, 64), tb, 0, stream>>>(Vw, VTw);

  attn_fwd<<<dim3(16, 64), dim3(256), 0, stream>>>(Qw, Kw, VTw, Yw);

  gemm_bt<0><<<dim3(8, 64), dim3(256), 0, stream>>>(
      Yw, wprojT, out, (u16*)nullptr, (u16*)nullptr, (u16*)nullptr,
      8192, 1024, 1024);
}